// Round 7
// baseline (1169.054 us; speedup 1.0000x reference)
//
#include <hip/hip_runtime.h>
#include <hip/hip_bf16.h>
#include <math.h>

#define DD 128

// diagnostic: fill output with a constant f32 pattern
__global__ void k_fill(float* __restrict__ out, float v, int n) {
    int i = blockIdx.x * 256 + threadIdx.x;
    if (i < n) out[i] = v;
}

// ---------------------------------------------------------------------------
// u_r[j] = sum_k w2_r[k] * W1_r[k][j] ; v_r[j] = sum_k w2_r[D+k] * W1_r[k][j]
__global__ void k_prep_uv(const float* __restrict__ W10, const float* __restrict__ W11,
                          const float* __restrict__ W12,
                          const float* __restrict__ w20, const float* __restrict__ w21,
                          const float* __restrict__ w22,
                          float* __restrict__ uv) {
    int r = blockIdx.x;            // 0..2
    int j = threadIdx.x;           // 0..127
    const float* W1 = (r==0) ? W10 : (r==1 ? W11 : W12);
    const float* w2 = (r==0) ? w20 : (r==1 ? w21 : w22);
    float u = 0.f, v = 0.f;
    for (int k = 0; k < DD; ++k) {
        float w = W1[k*DD + j];
        u += w2[k]      * w;
        v += w2[DD + k] * w;
    }
    uv[r*256 + j]      = u;
    uv[r*256 + DD + j] = v;
}

// M[c][j] = sum_k Wq[k][c] * Wk[k][j]  (q.k quadratic form: e_r = h_t^T M h_r)
__global__ void k_prep_M(const float* __restrict__ Wq, const float* __restrict__ Wk,
                         float* __restrict__ Mf) {
    int c = blockIdx.x, j = threadIdx.x;
    float acc = 0.f;
    for (int k = 0; k < DD; ++k)
        acc += Wq[k*DD + c] * Wk[k*DD + j];
    Mf[c*DD + j] = acc;
}

// scores: one thread per (relation, node)
__global__ void k_scores(const float* __restrict__ N, const float* __restrict__ uv,
                         float* __restrict__ sl, float* __restrict__ sr, int n) {
    int g = blockIdx.x * 256 + threadIdx.x;
    if (g >= 3*n) return;
    int r = g / n, i = g - r*n;
    const float* row = N + (size_t)i * DD;
    const float* u = uv + r*256;
    const float* v = u + DD;
    float a = 0.f, b = 0.f;
    for (int d = 0; d < DD; ++d) { float x = row[d]; a += x*u[d]; b += x*v[d]; }
    sl[(size_t)r*n + i] = a;
    sr[(size_t)r*n + i] = b;
}

// ---------------------------------------------------------------------------
// CSR build: count -> scan -> scatter
__global__ void k_count(const int* __restrict__ d0, const int* __restrict__ d1,
                        const int* __restrict__ d2,
                        unsigned* __restrict__ cnt, int n, int E) {
    int g = blockIdx.x * 256 + threadIdx.x;
    if (g >= 3*E) return;
    int r = (g >= 2*E) ? 2 : (g >= E ? 1 : 0);
    int e = g - r*E;
    const int* Dd = (r==0) ? d0 : (r==1 ? d1 : d2);
    atomicAdd(&cnt[(size_t)r*n + Dd[e]], 1u);
}

__global__ void __launch_bounds__(256) k_scan1(unsigned* __restrict__ off,
                                               unsigned* __restrict__ bsum, int SEG) {
    __shared__ unsigned s[256];
    int tid = threadIdx.x;
    int i = blockIdx.x * 256 + tid;
    unsigned v = (i < SEG) ? off[i] : 0u;
    s[tid] = v; __syncthreads();
#pragma unroll
    for (int o = 1; o < 256; o <<= 1) {
        unsigned a = (tid >= o) ? s[tid - o] : 0u; __syncthreads();
        s[tid] += a; __syncthreads();
    }
    if (i < SEG) off[i] = s[tid] - v;          // exclusive within block
    if (tid == 255) bsum[blockIdx.x] = s[255]; // block total
}

__global__ void __launch_bounds__(256) k_scan2(unsigned* __restrict__ bsum, int nb) {
    __shared__ unsigned s[256];
    __shared__ unsigned carry;
    int tid = threadIdx.x;
    if (tid == 0) carry = 0u;
    for (int base = 0; base < nb; base += 256) {
        int i = base + tid;
        unsigned v = (i < nb) ? bsum[i] : 0u;
        __syncthreads();
        s[tid] = v; __syncthreads();
#pragma unroll
        for (int o = 1; o < 256; o <<= 1) {
            unsigned a = (tid >= o) ? s[tid - o] : 0u; __syncthreads();
            s[tid] += a; __syncthreads();
        }
        unsigned incl = s[tid], tot = s[255], c = carry;
        if (i < nb) bsum[i] = c + incl - v;    // exclusive across blocks
        __syncthreads();
        if (tid == 0) carry = c + tot;
    }
}

__global__ void k_scan3(unsigned* __restrict__ off, const unsigned* __restrict__ bsum,
                        int SEG, unsigned total) {
    int i = blockIdx.x * 256 + threadIdx.x;
    if (i < SEG) off[i] += bsum[blockIdx.x];
    if (i == 0) off[SEG] = total;
}

__global__ void k_scatter(const int* __restrict__ s0, const int* __restrict__ d0,
                          const int* __restrict__ s1, const int* __restrict__ d1,
                          const int* __restrict__ s2, const int* __restrict__ d2,
                          const float* __restrict__ sl, const float* __restrict__ sr,
                          const unsigned* __restrict__ off, unsigned* __restrict__ cur,
                          int* __restrict__ esrc, float* __restrict__ ex, int n, int E) {
    int g = blockIdx.x * 256 + threadIdx.x;
    if (g >= 3*E) return;
    int r = (g >= 2*E) ? 2 : (g >= E ? 1 : 0);
    int e = g - r*E;
    const int* S  = (r==0) ? s0 : (r==1 ? s1 : s2);
    const int* Dd = (r==0) ? d0 : (r==1 ? d1 : d2);
    int si = S[e], di = Dd[e];
    size_t seg = (size_t)r*n + di;
    float x = sl[(size_t)r*n + si] + sr[seg];
    x = (x >= 0.f) ? x : 0.01f * x;            // leaky_relu
    unsigned p = off[seg] + atomicAdd(&cur[seg], 1u);
    esrc[p] = si;
    ex[p]   = x;
}

// ---------------------------------------------------------------------------
// k_node: fused per-node pass. One wave per node; lanes own cols 2l, 2l+1.
// Per relation: segment softmax over CSR in-edges, h_r = sum alpha*N[src] in regs.
// Then t = h_t @ M (f32 in LDS), e_r = t.h_r/sqrt(D), 3-way softmax, f32 store.
__global__ void __launch_bounds__(256) k_node(
        const float* __restrict__ N,
        const float* __restrict__ Mf,
        const unsigned* __restrict__ off,
        const int* __restrict__ esrc,
        const float* __restrict__ ex,
        const int* __restrict__ tgt,
        float* __restrict__ out, int n) {
    __shared__ float Ml[DD*DD];    // 64 KB, f32
    __shared__ float hsh[4][DD];
    int tid = threadIdx.x;
    {
        const uint4* msrc = (const uint4*)Mf;
        uint4* mdst = (uint4*)Ml;
#pragma unroll
        for (int it = 0; it < 16; ++it)        // 16384 f32 = 4096 uint4
            mdst[tid + it*256] = msrc[tid + it*256];
    }
    __syncthreads();
    int wave = tid >> 6, lane = tid & 63;
    int i = blockIdx.x * 4 + wave;
    if (i >= n) return;
    int t = tgt[0];
    t = (t < 0) ? 0 : (t > 2 ? 2 : t);         // safety clamp

    float hr0[3], hr1[3];
#pragma unroll
    for (int r = 0; r < 3; ++r) {
        size_t seg = (size_t)r*n + i;
        int a = (int)off[seg], b = (int)off[seg + 1];
        // segment max
        float m = -INFINITY;
        for (int j = a + lane; j < b; j += 64) m = fmaxf(m, ex[j]);
#pragma unroll
        for (int o = 32; o; o >>= 1) m = fmaxf(m, __shfl_xor(m, o));
        // segment exp-sum
        float s = 0.f;
        for (int j = a + lane; j < b; j += 64) s += __expf(ex[j] - m);
#pragma unroll
        for (int o = 32; o; o >>= 1) s += __shfl_xor(s, o);
        float inv_den = (b > a) ? 1.f / s : 0.f;
        // weighted feature sum (serial over in-edges, wave-wide over cols)
        float h0 = 0.f, h1 = 0.f;
        for (int j = a; j < b; ++j) {
            float al = __expf(ex[j] - m) * inv_den;
            float2 nv = ((const float2*)N)[(size_t)esrc[j] * 64 + lane];
            h0 += al * nv.x;
            h1 += al * nv.y;
        }
        hr0[r] = h0; hr1[r] = h1;
        if (r == t) { hsh[wave][2*lane] = h0; hsh[wave][2*lane + 1] = h1; }
    }

    // t-vec: t0 = (h_t M)[2*lane], t1 = (h_t M)[2*lane+1]
    float t0 = 0.f, t1 = 0.f;
    for (int c = 0; c < DD; ++c) {
        float hc = hsh[wave][c];               // LDS broadcast
        t0 += hc * Ml[c*DD + 2*lane];
        t1 += hc * Ml[c*DD + 2*lane + 1];
    }

    const float inv = 0.088388347648318447f;   // 1/sqrt(128)
    float e[3];
#pragma unroll
    for (int r = 0; r < 3; ++r) {
        float v = t0*hr0[r] + t1*hr1[r];
#pragma unroll
        for (int o = 32; o; o >>= 1) v += __shfl_xor(v, o);
        e[r] = v * inv;
    }
    float mx = fmaxf(e[0], fmaxf(e[1], e[2]));
    float x0 = __expf(e[0]-mx), x1 = __expf(e[1]-mx), x2 = __expf(e[2]-mx);
    float sinv = 1.f / (x0 + x1 + x2);
    float a0 = x0*sinv, a1 = x1*sinv, a2 = x2*sinv;
    float o0 = a0*hr0[0] + a1*hr0[1] + a2*hr0[2];
    float o1 = a0*hr1[0] + a1*hr1[1] + a2*hr1[2];
    ((float2*)(out + (size_t)i * DD))[lane] = make_float2(o0, o1);   // f32 output!
}

// ---------------------------------------------------------------------------
extern "C" void kernel_launch(void* const* d_in, const int* in_sizes, int n_in,
                              void* d_out, int out_size, void* d_ws, size_t ws_size,
                              hipStream_t stream) {
    float* outp = (float*)d_out;
    int fillgrid = (out_size + 255) / 256;
    if (n_in != 17) {                                  // marker: 1024.0
        k_fill<<<fillgrid, 256, 0, stream>>>(outp, 1024.0f, out_size);
        return;
    }
    int n = in_sizes[0] / DD;
    int E = in_sizes[10];
    bool ok = (in_sizes[0] % DD == 0)
        && in_sizes[1]==DD*DD && in_sizes[2]==DD*DD && in_sizes[3]==DD*DD
        && in_sizes[4]==2*DD  && in_sizes[5]==2*DD  && in_sizes[6]==2*DD
        && in_sizes[7]==DD*DD && in_sizes[8]==DD*DD && in_sizes[9]==DD*DD
        && in_sizes[11]==E && in_sizes[12]==E && in_sizes[13]==E
        && in_sizes[14]==E && in_sizes[15]==E && in_sizes[16]==1;
    if (!ok) {                                         // marker: 512.0
        k_fill<<<fillgrid, 256, 0, stream>>>(outp, 512.0f, out_size);
        return;
    }
    int SEG = 3*n;
    int NB1 = (SEG + 255) / 256;
    int tot = 3*E;

    // workspace (~19.3 MB): sl[3n] sr[3n] uv[768] Mf[16384] |
    //                       off[3n+1] cur[3n] bsum[NB1] | esrc[3E] ex[3E]
    size_t need_f = (size_t)SEG*2 + 768 + DD*DD + (SEG + 1) + SEG + NB1
                  + (size_t)tot*2;
    if (ws_size < need_f * sizeof(float)) {            // marker: 256.0
        k_fill<<<fillgrid, 256, 0, stream>>>(outp, 256.0f, out_size);
        return;
    }

    const float* N   = (const float*)d_in[0];
    const float* W10 = (const float*)d_in[1];
    const float* W11 = (const float*)d_in[2];
    const float* W12 = (const float*)d_in[3];
    const float* w20 = (const float*)d_in[4];
    const float* w21 = (const float*)d_in[5];
    const float* w22 = (const float*)d_in[6];
    const float* Wq  = (const float*)d_in[7];
    const float* Wk  = (const float*)d_in[8];
    // d_in[9] = Wv — computed but unused in the reference output
    const int* s0 = (const int*)d_in[10];
    const int* d0 = (const int*)d_in[11];
    const int* s1 = (const int*)d_in[12];
    const int* d1 = (const int*)d_in[13];
    const int* s2 = (const int*)d_in[14];
    const int* d2 = (const int*)d_in[15];
    const int* tgt = (const int*)d_in[16];

    float* ws = (float*)d_ws;
    float* sl = ws;
    float* sr = sl + SEG;
    float* uv = sr + SEG;
    float* Mf = uv + 768;
    unsigned* off  = (unsigned*)(Mf + DD*DD);
    unsigned* cur  = off + SEG + 1;
    unsigned* bsum = cur + SEG;
    int*   esrc = (int*)(bsum + NB1);
    float* ex   = (float*)(esrc + tot);

    hipMemsetAsync(off, 0, (size_t)(2*SEG + 1) * sizeof(unsigned), stream);

    k_prep_uv<<<3, DD, 0, stream>>>(W10, W11, W12, w20, w21, w22, uv);
    k_prep_M<<<DD, DD, 0, stream>>>(Wq, Wk, Mf);
    k_scores<<<(SEG + 255)/256, 256, 0, stream>>>(N, uv, sl, sr, n);
    k_count<<<(tot + 255)/256, 256, 0, stream>>>(d0, d1, d2, off, n, E);
    k_scan1<<<NB1, 256, 0, stream>>>(off, bsum, SEG);
    k_scan2<<<1, 256, 0, stream>>>(bsum, NB1);
    k_scan3<<<NB1, 256, 0, stream>>>(off, bsum, SEG, (unsigned)tot);
    k_scatter<<<(tot + 255)/256, 256, 0, stream>>>(s0,d0,s1,d1,s2,d2, sl,sr,
                                                   off, cur, esrc, ex, n, E);
    k_node<<<(n + 3)/4, 256, 0, stream>>>(N, Mf, off, esrc, ex, tgt, outp, n);
}

// Round 8
// 650.894 us; speedup vs baseline: 1.7961x; 1.7961x over previous
//
#include <hip/hip_runtime.h>
#include <hip/hip_bf16.h>
#include <math.h>

#define DD 128

// diagnostic: fill output with a constant f32 pattern
__global__ void k_fill(float* __restrict__ out, float v, int n) {
    int i = blockIdx.x * 256 + threadIdx.x;
    if (i < n) out[i] = v;
}

// ---------------------------------------------------------------------------
// u_r[j] = sum_k w2_r[k] * W1_r[k][j] ; v_r[j] = sum_k w2_r[D+k] * W1_r[k][j]
__global__ void k_prep_uv(const float* __restrict__ W10, const float* __restrict__ W11,
                          const float* __restrict__ W12,
                          const float* __restrict__ w20, const float* __restrict__ w21,
                          const float* __restrict__ w22,
                          float* __restrict__ uv) {
    int r = blockIdx.x;            // 0..2
    int j = threadIdx.x;           // 0..127
    const float* W1 = (r==0) ? W10 : (r==1 ? W11 : W12);
    const float* w2 = (r==0) ? w20 : (r==1 ? w21 : w22);
    float u = 0.f, v = 0.f;
    for (int k = 0; k < DD; ++k) {
        float w = W1[k*DD + j];
        u += w2[k]      * w;
        v += w2[DD + k] * w;
    }
    uv[r*256 + j]      = u;
    uv[r*256 + DD + j] = v;
}

// M[c][j] = sum_k Wq[k][c] * Wk[k][j]  (q.k quadratic form: e_r = h_t^T M h_r)
__global__ void k_prep_M(const float* __restrict__ Wq, const float* __restrict__ Wk,
                         float* __restrict__ Mf) {
    int c = blockIdx.x, j = threadIdx.x;
    float acc = 0.f;
    for (int k = 0; k < DD; ++k)
        acc += Wq[k*DD + c] * Wk[k*DD + j];
    Mf[c*DD + j] = acc;
}

// scores: one wave per node, coalesced float2 loads, 6 shuffle-dots
__global__ void __launch_bounds__(256) k_scores(
        const float* __restrict__ N, const float* __restrict__ uv,
        float* __restrict__ sl, float* __restrict__ sr, int n) {
    int wave = threadIdx.x >> 6, lane = threadIdx.x & 63;
    int i = blockIdx.x * 4 + wave;
    if (i >= n) return;
    float2 nv = ((const float2*)(N + (size_t)i * DD))[lane];
    float acc[6];
#pragma unroll
    for (int r = 0; r < 3; ++r) {
        float2 u = ((const float2*)(uv + r*256))[lane];
        float2 v = ((const float2*)(uv + r*256 + DD))[lane];
        acc[2*r]   = nv.x*u.x + nv.y*u.y;
        acc[2*r+1] = nv.x*v.x + nv.y*v.y;
    }
#pragma unroll
    for (int o = 32; o; o >>= 1) {
#pragma unroll
        for (int q = 0; q < 6; ++q) acc[q] += __shfl_xor(acc[q], o);
    }
    if (lane == 0) {
#pragma unroll
        for (int r = 0; r < 3; ++r) {
            sl[(size_t)r*n + i] = acc[2*r];
            sr[(size_t)r*n + i] = acc[2*r+1];
        }
    }
}

// ---------------------------------------------------------------------------
// CSR build: count -> scan -> scatter
__global__ void k_count(const int* __restrict__ d0, const int* __restrict__ d1,
                        const int* __restrict__ d2,
                        unsigned* __restrict__ cnt, int n, int E) {
    int g = blockIdx.x * 256 + threadIdx.x;
    if (g >= 3*E) return;
    int r = (g >= 2*E) ? 2 : (g >= E ? 1 : 0);
    int e = g - r*E;
    const int* Dd = (r==0) ? d0 : (r==1 ? d1 : d2);
    atomicAdd(&cnt[(size_t)r*n + Dd[e]], 1u);
}

__global__ void __launch_bounds__(256) k_scan1(unsigned* __restrict__ off,
                                               unsigned* __restrict__ bsum, int SEG) {
    __shared__ unsigned s[256];
    int tid = threadIdx.x;
    int i = blockIdx.x * 256 + tid;
    unsigned v = (i < SEG) ? off[i] : 0u;
    s[tid] = v; __syncthreads();
#pragma unroll
    for (int o = 1; o < 256; o <<= 1) {
        unsigned a = (tid >= o) ? s[tid - o] : 0u; __syncthreads();
        s[tid] += a; __syncthreads();
    }
    if (i < SEG) off[i] = s[tid] - v;          // exclusive within block
    if (tid == 255) bsum[blockIdx.x] = s[255]; // block total
}

__global__ void __launch_bounds__(256) k_scan2(unsigned* __restrict__ bsum, int nb) {
    __shared__ unsigned s[256];
    __shared__ unsigned carry;
    int tid = threadIdx.x;
    if (tid == 0) carry = 0u;
    for (int base = 0; base < nb; base += 256) {
        int i = base + tid;
        unsigned v = (i < nb) ? bsum[i] : 0u;
        __syncthreads();
        s[tid] = v; __syncthreads();
#pragma unroll
        for (int o = 1; o < 256; o <<= 1) {
            unsigned a = (tid >= o) ? s[tid - o] : 0u; __syncthreads();
            s[tid] += a; __syncthreads();
        }
        unsigned incl = s[tid], tot = s[255], c = carry;
        if (i < nb) bsum[i] = c + incl - v;    // exclusive across blocks
        __syncthreads();
        if (tid == 0) carry = c + tot;
    }
}

__global__ void k_scan3(unsigned* __restrict__ off, const unsigned* __restrict__ bsum,
                        int SEG, unsigned total) {
    int i = blockIdx.x * 256 + threadIdx.x;
    if (i < SEG) off[i] += bsum[blockIdx.x];
    if (i == 0) off[SEG] = total;
}

__global__ void k_scatter(const int* __restrict__ s0, const int* __restrict__ d0,
                          const int* __restrict__ s1, const int* __restrict__ d1,
                          const int* __restrict__ s2, const int* __restrict__ d2,
                          const float* __restrict__ sl, const float* __restrict__ sr,
                          const unsigned* __restrict__ off, unsigned* __restrict__ cur,
                          int* __restrict__ esrc, float* __restrict__ ex, int n, int E) {
    int g = blockIdx.x * 256 + threadIdx.x;
    if (g >= 3*E) return;
    int r = (g >= 2*E) ? 2 : (g >= E ? 1 : 0);
    int e = g - r*E;
    const int* S  = (r==0) ? s0 : (r==1 ? s1 : s2);
    const int* Dd = (r==0) ? d0 : (r==1 ? d1 : d2);
    int si = S[e], di = Dd[e];
    size_t seg = (size_t)r*n + di;
    float x = sl[(size_t)r*n + si] + sr[seg];
    x = (x >= 0.f) ? x : 0.01f * x;            // leaky_relu
    unsigned p = off[seg] + atomicAdd(&cur[seg], 1u);
    esrc[p] = si;
    ex[p]   = x;
}

// ---------------------------------------------------------------------------
// k_node: fused per-node pass. 1024-thread blocks (16 waves share one f32 M
// copy in LDS -> 72 KB total, ~20 waves/CU vs 8 before). Edge gathers take
// addresses from shfl broadcasts of pre-loaded (src, alpha) pairs -> no
// memory dependency in the gather loop, loads pipeline.
__global__ void __launch_bounds__(1024) k_node(
        const float* __restrict__ N,
        const float* __restrict__ Mf,
        const unsigned* __restrict__ off,
        const int* __restrict__ esrc,
        const float* __restrict__ ex,
        const int* __restrict__ tgt,
        float* __restrict__ out, int n) {
    __shared__ float Ml[DD*DD];     // 64 KB f32
    __shared__ float hsh[16][DD];   // 8 KB: per-wave h_target row
    int tid = threadIdx.x;
    {
        const uint4* msrc = (const uint4*)Mf;
        uint4* mdst = (uint4*)Ml;
#pragma unroll
        for (int it = 0; it < 4; ++it)         // 4096 uint4 / 1024 threads
            mdst[tid + it*1024] = msrc[tid + it*1024];
    }
    __syncthreads();
    int wave = tid >> 6, lane = tid & 63;
    int i = blockIdx.x * 16 + wave;
    if (i >= n) return;
    int t = tgt[0];
    t = (t < 0) ? 0 : (t > 2 ? 2 : t);

    const float2* N2 = (const float2*)N;
    float hr0[3], hr1[3];
#pragma unroll
    for (int r = 0; r < 3; ++r) {
        size_t seg = (size_t)r*n + i;
        int a = (int)off[seg], b = (int)off[seg + 1];
        // segment max (lane-parallel over contiguous ex)
        float m = -INFINITY;
        for (int j = a + lane; j < b; j += 64) m = fmaxf(m, ex[j]);
#pragma unroll
        for (int o = 32; o; o >>= 1) m = fmaxf(m, __shfl_xor(m, o));
        // segment exp-sum
        float s = 0.f;
        for (int j = a + lane; j < b; j += 64) s += __expf(ex[j] - m);
#pragma unroll
        for (int o = 32; o; o >>= 1) s += __shfl_xor(s, o);
        float inv_den = (b > a) ? 1.f / s : 0.f;
        // weighted feature sum: batch-load (src, alpha) into lanes, then
        // gather rows with shfl-broadcast addresses (pipelined loads)
        float h0 = 0.f, h1 = 0.f;
        for (int base = a; base < b; base += 64) {
            int rem = b - base;
            int cnt = rem < 64 ? rem : 64;
            int sj_l = 0; float al_l = 0.f;
            if (lane < cnt) {
                sj_l = esrc[base + lane];
                al_l = __expf(ex[base + lane] - m) * inv_den;
            }
            for (int j = 0; j < cnt; ++j) {
                int   sj = __shfl(sj_l, j);
                float aj = __shfl(al_l, j);
                float2 nv = N2[(size_t)sj * 64 + lane];
                h0 += aj * nv.x;
                h1 += aj * nv.y;
            }
        }
        hr0[r] = h0; hr1[r] = h1;
        if (r == t) { hsh[wave][2*lane] = h0; hsh[wave][2*lane + 1] = h1; }
    }
    // t-vec: t0 = (h_t M)[2*lane], t1 = (h_t M)[2*lane+1]
    // (hsh row is private to this wave: LDS write->read within a wave is safe)
    float t0 = 0.f, t1 = 0.f;
    const float2* Ml2 = (const float2*)Ml;
    for (int c = 0; c < DD; ++c) {
        float hc = hsh[wave][c];               // LDS broadcast
        float2 mv = Ml2[c*64 + lane];
        t0 += hc * mv.x;
        t1 += hc * mv.y;
    }

    const float inv = 0.088388347648318447f;   // 1/sqrt(128)
    float e[3];
#pragma unroll
    for (int r = 0; r < 3; ++r) {
        float v = t0*hr0[r] + t1*hr1[r];
#pragma unroll
        for (int o = 32; o; o >>= 1) v += __shfl_xor(v, o);
        e[r] = v * inv;
    }
    float mx = fmaxf(e[0], fmaxf(e[1], e[2]));
    float x0 = __expf(e[0]-mx), x1 = __expf(e[1]-mx), x2 = __expf(e[2]-mx);
    float sinv = 1.f / (x0 + x1 + x2);
    float a0 = x0*sinv, a1 = x1*sinv, a2 = x2*sinv;
    float o0 = a0*hr0[0] + a1*hr0[1] + a2*hr0[2];
    float o1 = a0*hr1[0] + a1*hr1[1] + a2*hr1[2];
    ((float2*)(out + (size_t)i * DD))[lane] = make_float2(o0, o1);
}

// ---------------------------------------------------------------------------
extern "C" void kernel_launch(void* const* d_in, const int* in_sizes, int n_in,
                              void* d_out, int out_size, void* d_ws, size_t ws_size,
                              hipStream_t stream) {
    float* outp = (float*)d_out;
    int fillgrid = (out_size + 255) / 256;
    if (n_in != 17) {                                  // marker: 1024.0
        k_fill<<<fillgrid, 256, 0, stream>>>(outp, 1024.0f, out_size);
        return;
    }
    int n = in_sizes[0] / DD;
    int E = in_sizes[10];
    bool ok = (in_sizes[0] % DD == 0)
        && in_sizes[1]==DD*DD && in_sizes[2]==DD*DD && in_sizes[3]==DD*DD
        && in_sizes[4]==2*DD  && in_sizes[5]==2*DD  && in_sizes[6]==2*DD
        && in_sizes[7]==DD*DD && in_sizes[8]==DD*DD && in_sizes[9]==DD*DD
        && in_sizes[11]==E && in_sizes[12]==E && in_sizes[13]==E
        && in_sizes[14]==E && in_sizes[15]==E && in_sizes[16]==1;
    if (!ok) {                                         // marker: 512.0
        k_fill<<<fillgrid, 256, 0, stream>>>(outp, 512.0f, out_size);
        return;
    }
    int SEG = 3*n;
    int NB1 = (SEG + 255) / 256;
    int tot = 3*E;

    // workspace (~19.3 MB): sl[3n] sr[3n] uv[768] Mf[16384] |
    //                       off[3n+1] cur[3n] bsum[NB1] | esrc[3E] ex[3E]
    size_t need_f = (size_t)SEG*2 + 768 + DD*DD + (SEG + 1) + SEG + NB1
                  + (size_t)tot*2;
    if (ws_size < need_f * sizeof(float)) {            // marker: 256.0
        k_fill<<<fillgrid, 256, 0, stream>>>(outp, 256.0f, out_size);
        return;
    }

    const float* N   = (const float*)d_in[0];
    const float* W10 = (const float*)d_in[1];
    const float* W11 = (const float*)d_in[2];
    const float* W12 = (const float*)d_in[3];
    const float* w20 = (const float*)d_in[4];
    const float* w21 = (const float*)d_in[5];
    const float* w22 = (const float*)d_in[6];
    const float* Wq  = (const float*)d_in[7];
    const float* Wk  = (const float*)d_in[8];
    // d_in[9] = Wv — computed but unused in the reference output
    const int* s0 = (const int*)d_in[10];
    const int* d0 = (const int*)d_in[11];
    const int* s1 = (const int*)d_in[12];
    const int* d1 = (const int*)d_in[13];
    const int* s2 = (const int*)d_in[14];
    const int* d2 = (const int*)d_in[15];
    const int* tgt = (const int*)d_in[16];

    float* ws = (float*)d_ws;
    float* sl = ws;
    float* sr = sl + SEG;
    float* uv = sr + SEG;
    float* Mf = uv + 768;
    unsigned* off  = (unsigned*)(Mf + DD*DD);
    unsigned* cur  = off + SEG + 1;
    unsigned* bsum = cur + SEG;
    int*   esrc = (int*)(bsum + NB1);
    float* ex   = (float*)(esrc + tot);

    hipMemsetAsync(off, 0, (size_t)(2*SEG + 1) * sizeof(unsigned), stream);

    k_prep_uv<<<3, DD, 0, stream>>>(W10, W11, W12, w20, w21, w22, uv);
    k_prep_M<<<DD, DD, 0, stream>>>(Wq, Wk, Mf);
    k_scores<<<(n + 3)/4, 256, 0, stream>>>(N, uv, sl, sr, n);
    k_count<<<(tot + 255)/256, 256, 0, stream>>>(d0, d1, d2, off, n, E);
    k_scan1<<<NB1, 256, 0, stream>>>(off, bsum, SEG);
    k_scan2<<<1, 256, 0, stream>>>(bsum, NB1);
    k_scan3<<<NB1, 256, 0, stream>>>(off, bsum, SEG, (unsigned)tot);
    k_scatter<<<(tot + 255)/256, 256, 0, stream>>>(s0,d0,s1,d1,s2,d2, sl,sr,
                                                   off, cur, esrc, ex, n, E);
    k_node<<<(n + 15)/16, 1024, 0, stream>>>(N, Mf, off, esrc, ex, tgt, outp, n);
}

// Round 9
// 518.195 us; speedup vs baseline: 2.2560x; 1.2561x over previous
//
#include <hip/hip_runtime.h>
#include <hip/hip_bf16.h>
#include <math.h>

#define DD 128

static __device__ __forceinline__ unsigned short f2bf(float f) {
    unsigned u = __float_as_uint(f);
    u += 0x7fffu + ((u >> 16) & 1u);   // RNE
    return (unsigned short)(u >> 16);
}
static __device__ __forceinline__ float bflo(unsigned mm) { return __uint_as_float(mm << 16); }
static __device__ __forceinline__ float bfhi(unsigned mm) { return __uint_as_float(mm & 0xffff0000u); }

// diagnostic: fill output with a constant f32 pattern
__global__ void k_fill(float* __restrict__ out, float v, int n) {
    int i = blockIdx.x * 256 + threadIdx.x;
    if (i < n) out[i] = v;
}

// ---------------------------------------------------------------------------
// fused prep: blocks 0..127 -> M[c][j] = sum_k Wq[k][c]*Wk[k][j]
//             blocks 128..130 -> u_r/v_r folds
__global__ void k_prep(const float* __restrict__ Wq, const float* __restrict__ Wk,
                       const float* __restrict__ W10, const float* __restrict__ W11,
                       const float* __restrict__ W12,
                       const float* __restrict__ w20, const float* __restrict__ w21,
                       const float* __restrict__ w22,
                       float* __restrict__ Mf, float* __restrict__ uv) {
    int b = blockIdx.x, j = threadIdx.x;
    if (b < DD) {
        float acc = 0.f;
        for (int k = 0; k < DD; ++k)
            acc += Wq[k*DD + b] * Wk[k*DD + j];
        Mf[b*DD + j] = acc;
    } else {
        int r = b - DD;
        const float* W1 = (r==0) ? W10 : (r==1 ? W11 : W12);
        const float* w2 = (r==0) ? w20 : (r==1 ? w21 : w22);
        float u = 0.f, v = 0.f;
        for (int k = 0; k < DD; ++k) {
            float w = W1[k*DD + j];
            u += w2[k]      * w;
            v += w2[DD + k] * w;
        }
        uv[r*256 + j]      = u;
        uv[r*256 + DD + j] = v;
    }
}

// N (f32) -> Nbf (bf16), 8 elems per thread
__global__ void __launch_bounds__(256) k_n2b(const float* __restrict__ N,
                                             unsigned* __restrict__ Nbf, int n8) {
    int g = blockIdx.x * 256 + threadIdx.x;
    if (g >= n8) return;
    const float4* N4 = (const float4*)N;
    float4 x = N4[2*g], y = N4[2*g + 1];
    uint4 o;
    o.x = (unsigned)f2bf(x.x) | ((unsigned)f2bf(x.y) << 16);
    o.y = (unsigned)f2bf(x.z) | ((unsigned)f2bf(x.w) << 16);
    o.z = (unsigned)f2bf(y.x) | ((unsigned)f2bf(y.y) << 16);
    o.w = (unsigned)f2bf(y.z) | ((unsigned)f2bf(y.w) << 16);
    ((uint4*)Nbf)[g] = o;
}

// scores: 2 nodes per wave (half-wave float4), f32 N for exactness
__global__ void __launch_bounds__(256) k_scores(
        const float* __restrict__ N, const float* __restrict__ uv,
        float* __restrict__ sl, float* __restrict__ sr, int n) {
    int tid = threadIdx.x;
    int wave = tid >> 6, lane = tid & 63, half = lane >> 5, l32 = lane & 31;
    int iw = blockIdx.x * 8 + wave * 2 + half;
    int i = (iw < n) ? iw : (n - 1);
    float4 nv = ((const float4*)N)[(size_t)i * 32 + l32];
    const float4* UV4 = (const float4*)uv;
    float acc[6];
#pragma unroll
    for (int r = 0; r < 3; ++r) {
        float4 u = UV4[r*64 + l32];
        float4 v = UV4[r*64 + 32 + l32];
        acc[2*r]   = nv.x*u.x + nv.y*u.y + nv.z*u.z + nv.w*u.w;
        acc[2*r+1] = nv.x*v.x + nv.y*v.y + nv.z*v.z + nv.w*v.w;
    }
#pragma unroll
    for (int o = 16; o; o >>= 1) {
#pragma unroll
        for (int q = 0; q < 6; ++q) acc[q] += __shfl_xor(acc[q], o);
    }
    if (l32 == 0 && iw < n) {
#pragma unroll
        for (int r = 0; r < 3; ++r) {
            sl[(size_t)r*n + iw] = acc[2*r];
            sr[(size_t)r*n + iw] = acc[2*r+1];
        }
    }
}

// ---------------------------------------------------------------------------
// CSR build: count -> scan -> scatter (edat packs {src, score-bits} in 8 B)
__global__ void k_count(const int* __restrict__ d0, const int* __restrict__ d1,
                        const int* __restrict__ d2,
                        unsigned* __restrict__ cnt, int n, int E) {
    int g = blockIdx.x * 256 + threadIdx.x;
    if (g >= 3*E) return;
    int r = (g >= 2*E) ? 2 : (g >= E ? 1 : 0);
    int e = g - r*E;
    const int* Dd = (r==0) ? d0 : (r==1 ? d1 : d2);
    atomicAdd(&cnt[(size_t)r*n + Dd[e]], 1u);
}

__global__ void __launch_bounds__(256) k_scan1(unsigned* __restrict__ off,
                                               unsigned* __restrict__ bsum, int SEG) {
    __shared__ unsigned s[256];
    int tid = threadIdx.x;
    int i = blockIdx.x * 256 + tid;
    unsigned v = (i < SEG) ? off[i] : 0u;
    s[tid] = v; __syncthreads();
#pragma unroll
    for (int o = 1; o < 256; o <<= 1) {
        unsigned a = (tid >= o) ? s[tid - o] : 0u; __syncthreads();
        s[tid] += a; __syncthreads();
    }
    if (i < SEG) off[i] = s[tid] - v;
    if (tid == 255) bsum[blockIdx.x] = s[255];
}

__global__ void __launch_bounds__(256) k_scan2(unsigned* __restrict__ bsum, int nb) {
    __shared__ unsigned s[256];
    __shared__ unsigned carry;
    int tid = threadIdx.x;
    if (tid == 0) carry = 0u;
    for (int base = 0; base < nb; base += 256) {
        int i = base + tid;
        unsigned v = (i < nb) ? bsum[i] : 0u;
        __syncthreads();
        s[tid] = v; __syncthreads();
#pragma unroll
        for (int o = 1; o < 256; o <<= 1) {
            unsigned a = (tid >= o) ? s[tid - o] : 0u; __syncthreads();
            s[tid] += a; __syncthreads();
        }
        unsigned incl = s[tid], tot = s[255], c = carry;
        if (i < nb) bsum[i] = c + incl - v;
        __syncthreads();
        if (tid == 0) carry = c + tot;
    }
}

__global__ void k_scan3(unsigned* __restrict__ off, const unsigned* __restrict__ bsum,
                        int SEG, unsigned total) {
    int i = blockIdx.x * 256 + threadIdx.x;
    if (i < SEG) off[i] += bsum[blockIdx.x];
    if (i == 0) off[SEG] = total;
}

__global__ void k_scatter(const int* __restrict__ s0, const int* __restrict__ d0,
                          const int* __restrict__ s1, const int* __restrict__ d1,
                          const int* __restrict__ s2, const int* __restrict__ d2,
                          const float* __restrict__ sl, const float* __restrict__ sr,
                          const unsigned* __restrict__ off, unsigned* __restrict__ cur,
                          uint2* __restrict__ edat, int n, int E) {
    int g = blockIdx.x * 256 + threadIdx.x;
    if (g >= 3*E) return;
    int r = (g >= 2*E) ? 2 : (g >= E ? 1 : 0);
    int e = g - r*E;
    const int* S  = (r==0) ? s0 : (r==1 ? s1 : s2);
    const int* Dd = (r==0) ? d0 : (r==1 ? d1 : d2);
    int si = S[e], di = Dd[e];
    size_t seg = (size_t)r*n + di;
    float x = sl[(size_t)r*n + si] + sr[seg];
    x = (x >= 0.f) ? x : 0.01f * x;            // leaky_relu
    unsigned p = off[seg] + atomicAdd(&cur[seg], 1u);
    edat[p] = make_uint2((unsigned)si, __float_as_uint(x));
}

// ---------------------------------------------------------------------------
// pair-gather: lanes 0-31 take even edges, 32-63 odd; 4 cols/lane; 2 pair
// slots per iteration -> 4 edges / 2 loads in flight; masked alphas (no tail).
static __device__ __forceinline__ void gather_pairs(
        const uint2* __restrict__ Nbf, int sj_l, float al_l, int cc,
        int half, int l32, float h[4]) {
    for (int p = 0; p < cc; p += 4) {
        int i0 = p + half, i1 = p + 2 + half;
        int e0 = (i0 < cc) ? i0 : cc - 1;
        int e1 = (i1 < cc) ? i1 : cc - 1;
        float a0 = __shfl(al_l, e0); a0 = (i0 < cc) ? a0 : 0.f;
        float a1 = __shfl(al_l, e1); a1 = (i1 < cc) ? a1 : 0.f;
        int s0 = __shfl(sj_l, e0);
        int s1 = __shfl(sj_l, e1);
        uint2 v0 = Nbf[(size_t)s0 * 32 + l32];
        uint2 v1 = Nbf[(size_t)s1 * 32 + l32];
        h[0] += a0*bflo(v0.x) + a1*bflo(v1.x);
        h[1] += a0*bfhi(v0.x) + a1*bfhi(v1.x);
        h[2] += a0*bflo(v0.y) + a1*bflo(v1.y);
        h[3] += a0*bfhi(v0.y) + a1*bfhi(v1.y);
    }
}

// k_node: fused per-node pass, 1024-thread blocks share f32 M in LDS.
__global__ void __launch_bounds__(1024) k_node(
        const uint2* __restrict__ Nbf,
        const float* __restrict__ Mf,
        const unsigned* __restrict__ off,
        const uint2* __restrict__ edat,
        const int* __restrict__ tgt,
        float* __restrict__ out, int n) {
    __shared__ float Ml[DD*DD];     // 64 KB f32
    __shared__ float hsh[16][DD];   // 8 KB
    int tid = threadIdx.x;
    {
        const uint4* msrc = (const uint4*)Mf;
        uint4* mdst = (uint4*)Ml;
#pragma unroll
        for (int it = 0; it < 4; ++it)
            mdst[tid + it*1024] = msrc[tid + it*1024];
    }
    __syncthreads();
    int wave = tid >> 6, lane = tid & 63, half = lane >> 5, l32 = lane & 31;
    int i = blockIdx.x * 16 + wave;
    if (i >= n) return;
    int t = tgt[0];
    t = (t < 0) ? 0 : (t > 2 ? 2 : t);

    // prefetch all six CSR bounds (independent loads)
    int a0 = (int)off[i],       b0 = (int)off[i + 1];
    int a1 = (int)off[n + i],   b1 = (int)off[n + i + 1];
    int a2 = (int)off[2*n + i], b2 = (int)off[2*n + i + 1];

    float hr[3][4];
#pragma unroll
    for (int r = 0; r < 3; ++r) {
        int a = (r==0) ? a0 : (r==1 ? a1 : a2);
        int b = (r==0) ? b0 : (r==1 ? b1 : b2);
        int cnt = b - a;
        float h[4] = {0.f, 0.f, 0.f, 0.f};
        if (cnt > 0 && cnt <= 64) {
            // register-resident fast path
            uint2 ed = (lane < cnt) ? edat[a + lane] : make_uint2(0u, 0u);
            int sj_l = (int)ed.x;
            float x_l = (lane < cnt) ? __uint_as_float(ed.y) : -INFINITY;
            float m = x_l;
#pragma unroll
            for (int o = 32; o; o >>= 1) m = fmaxf(m, __shfl_xor(m, o));
            float e_l = (lane < cnt) ? __expf(x_l - m) : 0.f;
            float s = e_l;
#pragma unroll
            for (int o = 32; o; o >>= 1) s += __shfl_xor(s, o);
            float al_l = e_l / s;
            gather_pairs(Nbf, sj_l, al_l, cnt, half, l32, h);
        } else if (cnt > 64) {
            // general path
            float m = -INFINITY;
            for (int j = a + lane; j < b; j += 64)
                m = fmaxf(m, __uint_as_float(edat[j].y));
#pragma unroll
            for (int o = 32; o; o >>= 1) m = fmaxf(m, __shfl_xor(m, o));
            float s = 0.f;
            for (int j = a + lane; j < b; j += 64)
                s += __expf(__uint_as_float(edat[j].y) - m);
#pragma unroll
            for (int o = 32; o; o >>= 1) s += __shfl_xor(s, o);
            float inv_den = 1.f / s;
            for (int base = a; base < b; base += 64) {
                int cc = b - base; if (cc > 64) cc = 64;
                uint2 ed = (lane < cc) ? edat[base + lane] : make_uint2(0u, 0u);
                int sj_l = (int)ed.x;
                float al_l = (lane < cc)
                    ? __expf(__uint_as_float(ed.y) - m) * inv_den : 0.f;
                gather_pairs(Nbf, sj_l, al_l, cc, half, l32, h);
            }
        }
        // combine the two half-wave partial sums
#pragma unroll
        for (int q = 0; q < 4; ++q) {
            h[q] += __shfl_xor(h[q], 32);
            hr[r][q] = h[q];
        }
        if (r == t && half == 0)
            ((float4*)&hsh[wave][0])[l32] =
                make_float4(h[0], h[1], h[2], h[3]);
    }

    // t-vec: t4[q] = (h_t M)[4*l32+q], c-range split across half-waves
    float t4[4] = {0.f, 0.f, 0.f, 0.f};
    const float4* Ml4 = (const float4*)Ml;
    int c0 = half * 64;
    for (int c = c0; c < c0 + 64; ++c) {
        float hc = hsh[wave][c];               // LDS broadcast
        float4 mv = Ml4[c*32 + l32];
        t4[0] += hc*mv.x; t4[1] += hc*mv.y; t4[2] += hc*mv.z; t4[3] += hc*mv.w;
    }
#pragma unroll
    for (int q = 0; q < 4; ++q) t4[q] += __shfl_xor(t4[q], 32);

    const float inv = 0.088388347648318447f;   // 1/sqrt(128)
    float e[3];
#pragma unroll
    for (int r = 0; r < 3; ++r) {
        float v = t4[0]*hr[r][0] + t4[1]*hr[r][1] + t4[2]*hr[r][2] + t4[3]*hr[r][3];
#pragma unroll
        for (int o = 16; o; o >>= 1) v += __shfl_xor(v, o);   // half-wave dot
        e[r] = v * inv;
    }
    float mx = fmaxf(e[0], fmaxf(e[1], e[2]));
    float x0 = __expf(e[0]-mx), x1 = __expf(e[1]-mx), x2 = __expf(e[2]-mx);
    float sinv = 1.f / (x0 + x1 + x2);
    float aw0 = x0*sinv, aw1 = x1*sinv, aw2 = x2*sinv;
    if (half == 0) {
        float4 o4;
        o4.x = aw0*hr[0][0] + aw1*hr[1][0] + aw2*hr[2][0];
        o4.y = aw0*hr[0][1] + aw1*hr[1][1] + aw2*hr[2][1];
        o4.z = aw0*hr[0][2] + aw1*hr[1][2] + aw2*hr[2][2];
        o4.w = aw0*hr[0][3] + aw1*hr[1][3] + aw2*hr[2][3];
        ((float4*)(out + (size_t)i * DD))[l32] = o4;
    }
}

// ---------------------------------------------------------------------------
extern "C" void kernel_launch(void* const* d_in, const int* in_sizes, int n_in,
                              void* d_out, int out_size, void* d_ws, size_t ws_size,
                              hipStream_t stream) {
    float* outp = (float*)d_out;
    int fillgrid = (out_size + 255) / 256;
    if (n_in != 17) {                                  // marker: 1024.0
        k_fill<<<fillgrid, 256, 0, stream>>>(outp, 1024.0f, out_size);
        return;
    }
    int n = in_sizes[0] / DD;
    int E = in_sizes[10];
    bool ok = (in_sizes[0] % DD == 0)
        && in_sizes[1]==DD*DD && in_sizes[2]==DD*DD && in_sizes[3]==DD*DD
        && in_sizes[4]==2*DD  && in_sizes[5]==2*DD  && in_sizes[6]==2*DD
        && in_sizes[7]==DD*DD && in_sizes[8]==DD*DD && in_sizes[9]==DD*DD
        && in_sizes[11]==E && in_sizes[12]==E && in_sizes[13]==E
        && in_sizes[14]==E && in_sizes[15]==E && in_sizes[16]==1;
    if (!ok) {                                         // marker: 512.0
        k_fill<<<fillgrid, 256, 0, stream>>>(outp, 512.0f, out_size);
        return;
    }
    int SEG = 3*n;
    int NB1 = (SEG + 255) / 256;
    int tot = 3*E;

    // workspace (floats): sl[3n] sr[3n] uv[768] Mf[16384] off[3n+1] cur[3n]
    //                     bsum[NB1] | edat[3E]*2 (8B-aligned) | Nbf[n*64] (16B-aligned)
    size_t o_edat = (size_t)2*SEG + 768 + DD*DD + (SEG + 1) + SEG + NB1;
    o_edat = (o_edat + 1) & ~(size_t)1;
    size_t o_nbf = o_edat + (size_t)2*tot;
    o_nbf = (o_nbf + 3) & ~(size_t)3;
    size_t need_f = o_nbf + (size_t)n*64;
    if (ws_size < need_f * sizeof(float)) {            // marker: 256.0
        k_fill<<<fillgrid, 256, 0, stream>>>(outp, 256.0f, out_size);
        return;
    }

    const float* N   = (const float*)d_in[0];
    const float* W10 = (const float*)d_in[1];
    const float* W11 = (const float*)d_in[2];
    const float* W12 = (const float*)d_in[3];
    const float* w20 = (const float*)d_in[4];
    const float* w21 = (const float*)d_in[5];
    const float* w22 = (const float*)d_in[6];
    const float* Wq  = (const float*)d_in[7];
    const float* Wk  = (const float*)d_in[8];
    // d_in[9] = Wv — unused in the reference output
    const int* s0 = (const int*)d_in[10];
    const int* d0 = (const int*)d_in[11];
    const int* s1 = (const int*)d_in[12];
    const int* d1 = (const int*)d_in[13];
    const int* s2 = (const int*)d_in[14];
    const int* d2 = (const int*)d_in[15];
    const int* tgt = (const int*)d_in[16];

    float* ws = (float*)d_ws;
    float* sl = ws;
    float* sr = sl + SEG;
    float* uv = sr + SEG;
    float* Mf = uv + 768;
    unsigned* off  = (unsigned*)(Mf + DD*DD);
    unsigned* cur  = off + SEG + 1;
    unsigned* bsum = cur + SEG;
    uint2*    edat = (uint2*)(ws + o_edat);
    unsigned* Nbf  = (unsigned*)(ws + o_nbf);

    hipMemsetAsync(off, 0, (size_t)(2*SEG + 1) * sizeof(unsigned), stream);

    k_prep<<<DD + 3, DD, 0, stream>>>(Wq, Wk, W10, W11, W12, w20, w21, w22, Mf, uv);
    k_n2b<<<(16*n + 255)/256, 256, 0, stream>>>(N, Nbf, 16*n);
    k_scores<<<(n + 7)/8, 256, 0, stream>>>(N, uv, sl, sr, n);
    k_count<<<(tot + 255)/256, 256, 0, stream>>>(d0, d1, d2, off, n, E);
    k_scan1<<<NB1, 256, 0, stream>>>(off, bsum, SEG);
    k_scan2<<<1, 256, 0, stream>>>(bsum, NB1);
    k_scan3<<<NB1, 256, 0, stream>>>(off, bsum, SEG, (unsigned)tot);
    k_scatter<<<(tot + 255)/256, 256, 0, stream>>>(s0,d0,s1,d1,s2,d2, sl,sr,
                                                   off, cur, edat, n, E);
    k_node<<<(n + 15)/16, 1024, 0, stream>>>((const uint2*)Nbf, Mf, off, edat,
                                             tgt, outp, n);
}

// Round 10
// 515.633 us; speedup vs baseline: 2.2672x; 1.0050x over previous
//
#include <hip/hip_runtime.h>
#include <hip/hip_bf16.h>
#include <math.h>

#define DD 128

static __device__ __forceinline__ unsigned short f2bf(float f) {
    unsigned u = __float_as_uint(f);
    u += 0x7fffu + ((u >> 16) & 1u);   // RNE
    return (unsigned short)(u >> 16);
}
static __device__ __forceinline__ float bflo(unsigned mm) { return __uint_as_float(mm << 16); }
static __device__ __forceinline__ float bfhi(unsigned mm) { return __uint_as_float(mm & 0xffff0000u); }

// diagnostic marker fill
__global__ void k_fill(float* __restrict__ out, float v, int n) {
    int i = blockIdx.x * 256 + threadIdx.x;
    if (i < n) out[i] = v;
}

// ---------------------------------------------------------------------------
// fused prep: blocks 0..127 -> M[c][j] = sum_k Wq[k][c]*Wk[k][j]
//             blocks 128..130 -> u_r/v_r folds
__global__ void k_prep(const float* __restrict__ Wq, const float* __restrict__ Wk,
                       const float* __restrict__ W10, const float* __restrict__ W11,
                       const float* __restrict__ W12,
                       const float* __restrict__ w20, const float* __restrict__ w21,
                       const float* __restrict__ w22,
                       float* __restrict__ Mf, float* __restrict__ uv) {
    int b = blockIdx.x, j = threadIdx.x;
    if (b < DD) {
        float acc = 0.f;
        for (int k = 0; k < DD; ++k)
            acc += Wq[k*DD + b] * Wk[k*DD + j];
        Mf[b*DD + j] = acc;
    } else {
        int r = b - DD;
        const float* W1 = (r==0) ? W10 : (r==1 ? W11 : W12);
        const float* w2 = (r==0) ? w20 : (r==1 ? w21 : w22);
        float u = 0.f, v = 0.f;
        for (int k = 0; k < DD; ++k) {
            float w = W1[k*DD + j];
            u += w2[k]      * w;
            v += w2[DD + k] * w;
        }
        uv[r*256 + j]      = u;
        uv[r*256 + DD + j] = v;
    }
}

// ---------------------------------------------------------------------------
// k_scores: 2 nodes/wave (half-wave float4). Also emits bf16 N copy and
// zeroes the CSR counters (grid covers 3.2M threads >> SEG).
__global__ void __launch_bounds__(256) k_scores(
        const float* __restrict__ N, const float* __restrict__ uv,
        float* __restrict__ sl, float* __restrict__ sr,
        uint2* __restrict__ Nbf, unsigned* __restrict__ cnt,
        int n, int SEG) {
    int g0 = blockIdx.x * 256 + threadIdx.x;
    if (g0 < SEG) cnt[g0] = 0u;
    int tid = threadIdx.x;
    int wave = tid >> 6, lane = tid & 63, half = lane >> 5, l32 = lane & 31;
    int iw = blockIdx.x * 8 + wave * 2 + half;
    int i = (iw < n) ? iw : (n - 1);
    float4 nv = ((const float4*)N)[(size_t)i * 32 + l32];
    if (iw < n) {
        uint2 pk;
        pk.x = (unsigned)f2bf(nv.x) | ((unsigned)f2bf(nv.y) << 16);
        pk.y = (unsigned)f2bf(nv.z) | ((unsigned)f2bf(nv.w) << 16);
        Nbf[(size_t)iw * 32 + l32] = pk;
    }
    const float4* UV4 = (const float4*)uv;
    float acc[6];
#pragma unroll
    for (int r = 0; r < 3; ++r) {
        float4 u = UV4[r*64 + l32];
        float4 v = UV4[r*64 + 32 + l32];
        acc[2*r]   = nv.x*u.x + nv.y*u.y + nv.z*u.z + nv.w*u.w;
        acc[2*r+1] = nv.x*v.x + nv.y*v.y + nv.z*v.z + nv.w*v.w;
    }
#pragma unroll
    for (int o = 16; o; o >>= 1) {
#pragma unroll
        for (int q = 0; q < 6; ++q) acc[q] += __shfl_xor(acc[q], o);
    }
    if (l32 == 0 && iw < n) {
#pragma unroll
        for (int r = 0; r < 3; ++r) {
            sl[(size_t)r*n + iw] = acc[2*r];
            sr[(size_t)r*n + iw] = acc[2*r+1];
        }
    }
}

// ---------------------------------------------------------------------------
// count + per-edge rank (kills scatter's atomics)
__global__ void k_count(const int* __restrict__ d0, const int* __restrict__ d1,
                        const int* __restrict__ d2,
                        unsigned* __restrict__ cnt, unsigned* __restrict__ rank,
                        int n, int E) {
    int g = blockIdx.x * 256 + threadIdx.x;
    if (g >= 3*E) return;
    int r = (g >= 2*E) ? 2 : (g >= E ? 1 : 0);
    int e = g - r*E;
    const int* Dd = (r==0) ? d0 : (r==1 ? d1 : d2);
    rank[g] = atomicAdd(&cnt[(size_t)r*n + Dd[e]], 1u);
}

__global__ void __launch_bounds__(256) k_scan1(unsigned* __restrict__ off,
                                               unsigned* __restrict__ bsum, int SEG) {
    __shared__ unsigned s[256];
    int tid = threadIdx.x;
    int i = blockIdx.x * 256 + tid;
    unsigned v = (i < SEG) ? off[i] : 0u;
    s[tid] = v; __syncthreads();
#pragma unroll
    for (int o = 1; o < 256; o <<= 1) {
        unsigned a = (tid >= o) ? s[tid - o] : 0u; __syncthreads();
        s[tid] += a; __syncthreads();
    }
    if (i < SEG) off[i] = s[tid] - v;          // exclusive within block
    if (tid == 255) bsum[blockIdx.x] = s[255]; // block total
}

__global__ void __launch_bounds__(256) k_scan2(unsigned* __restrict__ bsum, int nb) {
    __shared__ unsigned s[256];
    __shared__ unsigned carry;
    int tid = threadIdx.x;
    if (tid == 0) carry = 0u;
    for (int base = 0; base < nb; base += 256) {
        int i = base + tid;
        unsigned v = (i < nb) ? bsum[i] : 0u;
        __syncthreads();
        s[tid] = v; __syncthreads();
#pragma unroll
        for (int o = 1; o < 256; o <<= 1) {
            unsigned a = (tid >= o) ? s[tid - o] : 0u; __syncthreads();
            s[tid] += a; __syncthreads();
        }
        unsigned incl = s[tid], tot = s[255], c = carry;
        if (i < nb) bsum[i] = c + incl - v;    // exclusive across blocks
        __syncthreads();
        if (tid == 0) carry = c + tot;
    }
}

// scatter with precomputed rank — no atomics
__global__ void k_scatter(const int* __restrict__ s0, const int* __restrict__ d0,
                          const int* __restrict__ s1, const int* __restrict__ d1,
                          const int* __restrict__ s2, const int* __restrict__ d2,
                          const float* __restrict__ sl, const float* __restrict__ sr,
                          const unsigned* __restrict__ off,
                          const unsigned* __restrict__ bsum,
                          const unsigned* __restrict__ rank,
                          uint2* __restrict__ edat, int n, int E) {
    int g = blockIdx.x * 256 + threadIdx.x;
    if (g >= 3*E) return;
    int r = (g >= 2*E) ? 2 : (g >= E ? 1 : 0);
    int e = g - r*E;
    const int* S  = (r==0) ? s0 : (r==1 ? s1 : s2);
    const int* Dd = (r==0) ? d0 : (r==1 ? d1 : d2);
    int si = S[e], di = Dd[e];
    int seg = r*n + di;
    float x = sl[(size_t)r*n + si] + sr[seg];
    x = (x >= 0.f) ? x : 0.01f * x;            // leaky_relu
    unsigned p = off[seg] + bsum[seg >> 8] + rank[g];
    edat[p] = make_uint2((unsigned)si, __float_as_uint(x));
}

// ---------------------------------------------------------------------------
// quarter-wave gather: 16 lanes/edge x uint4 (16 B) -> 1 load per lane per
// 4 edges; 8 cols/lane; masked alphas (no tail).
static __device__ __forceinline__ void gather_quads(
        const uint4* __restrict__ Nbf, int sj_l, float al_l, int cc,
        int q, int l16, float h[8]) {
    for (int p = 0; p < cc; p += 4) {
        int idx = p + q;
        int e0 = (idx < cc) ? idx : cc - 1;
        float a0 = __shfl(al_l, e0); a0 = (idx < cc) ? a0 : 0.f;
        int s0 = __shfl(sj_l, e0);
        uint4 v = Nbf[(size_t)s0 * 16 + l16];
        h[0] += a0*bflo(v.x); h[1] += a0*bfhi(v.x);
        h[2] += a0*bflo(v.y); h[3] += a0*bfhi(v.y);
        h[4] += a0*bflo(v.z); h[5] += a0*bfhi(v.z);
        h[6] += a0*bflo(v.w); h[7] += a0*bfhi(v.w);
    }
}

// k_node: fused per-node pass, 1024-thread blocks share f32 M in LDS.
__global__ void __launch_bounds__(1024) k_node(
        const uint4* __restrict__ Nbf,
        const float* __restrict__ Mf,
        const unsigned* __restrict__ off,
        const unsigned* __restrict__ bsum,
        const uint2* __restrict__ edat,
        const int* __restrict__ tgt,
        float* __restrict__ out, int n, int TOT) {
    __shared__ float Ml[DD*DD];     // 64 KB f32
    __shared__ float hsh[16][DD];   // 8 KB
    int tid = threadIdx.x;
    {
        const uint4* msrc = (const uint4*)Mf;
        uint4* mdst = (uint4*)Ml;
#pragma unroll
        for (int it = 0; it < 4; ++it)
            mdst[tid + it*1024] = msrc[tid + it*1024];
    }
    __syncthreads();
    int wave = tid >> 6, lane = tid & 63, q = lane >> 4, l16 = lane & 15;
    int i = blockIdx.x * 16 + wave;
    if (i >= n) return;
    int t = tgt[0];
    t = (t < 0) ? 0 : (t > 2 ? 2 : t);
    int SEG = 3*n;

    float hr[3][8];
#pragma unroll
    for (int r = 0; r < 3; ++r) {
        int seg = r*n + i;
        int a = (int)(off[seg] + bsum[seg >> 8]);
        int b = (seg + 1 < SEG) ? (int)(off[seg+1] + bsum[(seg+1) >> 8]) : TOT;
        int cnt = b - a;
        float h[8] = {0.f,0.f,0.f,0.f,0.f,0.f,0.f,0.f};
        if (cnt > 0 && cnt <= 64) {
            uint2 ed = (lane < cnt) ? edat[a + lane] : make_uint2(0u, 0u);
            int sj_l = (int)ed.x;
            float x_l = (lane < cnt) ? __uint_as_float(ed.y) : -INFINITY;
            float m = x_l;
#pragma unroll
            for (int o = 32; o; o >>= 1) m = fmaxf(m, __shfl_xor(m, o));
            float e_l = (lane < cnt) ? __expf(x_l - m) : 0.f;
            float s = e_l;
#pragma unroll
            for (int o = 32; o; o >>= 1) s += __shfl_xor(s, o);
            float al_l = e_l / s;
            gather_quads(Nbf, sj_l, al_l, cnt, q, l16, h);
        } else if (cnt > 64) {
            float m = -INFINITY;
            for (int j = a + lane; j < b; j += 64)
                m = fmaxf(m, __uint_as_float(edat[j].y));
#pragma unroll
            for (int o = 32; o; o >>= 1) m = fmaxf(m, __shfl_xor(m, o));
            float s = 0.f;
            for (int j = a + lane; j < b; j += 64)
                s += __expf(__uint_as_float(edat[j].y) - m);
#pragma unroll
            for (int o = 32; o; o >>= 1) s += __shfl_xor(s, o);
            float inv_den = 1.f / s;
            for (int base = a; base < b; base += 64) {
                int cc = b - base; if (cc > 64) cc = 64;
                uint2 ed = (lane < cc) ? edat[base + lane] : make_uint2(0u, 0u);
                int sj_l = (int)ed.x;
                float al_l = (lane < cc)
                    ? __expf(__uint_as_float(ed.y) - m) * inv_den : 0.f;
                gather_quads(Nbf, sj_l, al_l, cc, q, l16, h);
            }
        }
        // reduce partial sums across the 4 quarter-wave groups
#pragma unroll
        for (int k = 0; k < 8; ++k) {
            h[k] += __shfl_xor(h[k], 16);
            h[k] += __shfl_xor(h[k], 32);
            hr[r][k] = h[k];
        }
        if (r == t && q == 0) {
            ((float4*)&hsh[wave][0])[2*l16]     = make_float4(h[0],h[1],h[2],h[3]);
            ((float4*)&hsh[wave][0])[2*l16 + 1] = make_float4(h[4],h[5],h[6],h[7]);
        }
    }

    // t-vec: t8[k] = (h_t M)[8*l16+k]; c-range split across quarter-waves
    float t8[8] = {0.f,0.f,0.f,0.f,0.f,0.f,0.f,0.f};
    const float4* Ml4 = (const float4*)Ml;
    int c0 = q * 32;
    for (int c = c0; c < c0 + 32; ++c) {
        float hc = hsh[wave][c];               // LDS broadcast
        float4 m0 = Ml4[c*32 + 2*l16];
        float4 m1 = Ml4[c*32 + 2*l16 + 1];
        t8[0] += hc*m0.x; t8[1] += hc*m0.y; t8[2] += hc*m0.z; t8[3] += hc*m0.w;
        t8[4] += hc*m1.x; t8[5] += hc*m1.y; t8[6] += hc*m1.z; t8[7] += hc*m1.w;
    }
#pragma unroll
    for (int k = 0; k < 8; ++k) {
        t8[k] += __shfl_xor(t8[k], 16);
        t8[k] += __shfl_xor(t8[k], 32);
    }

    const float inv = 0.088388347648318447f;   // 1/sqrt(128)
    float e[3];
#pragma unroll
    for (int r = 0; r < 3; ++r) {
        float v = 0.f;
#pragma unroll
        for (int k = 0; k < 8; ++k) v += t8[k]*hr[r][k];
#pragma unroll
        for (int o = 8; o; o >>= 1) v += __shfl_xor(v, o);   // over l16
        e[r] = v * inv;
    }
    float mx = fmaxf(e[0], fmaxf(e[1], e[2]));
    float x0 = __expf(e[0]-mx), x1 = __expf(e[1]-mx), x2 = __expf(e[2]-mx);
    float sinv = 1.f / (x0 + x1 + x2);
    float aw0 = x0*sinv, aw1 = x1*sinv, aw2 = x2*sinv;
    if (q == 0) {
        float4 oa, ob;
        oa.x = aw0*hr[0][0] + aw1*hr[1][0] + aw2*hr[2][0];
        oa.y = aw0*hr[0][1] + aw1*hr[1][1] + aw2*hr[2][1];
        oa.z = aw0*hr[0][2] + aw1*hr[1][2] + aw2*hr[2][2];
        oa.w = aw0*hr[0][3] + aw1*hr[1][3] + aw2*hr[2][3];
        ob.x = aw0*hr[0][4] + aw1*hr[1][4] + aw2*hr[2][4];
        ob.y = aw0*hr[0][5] + aw1*hr[1][5] + aw2*hr[2][5];
        ob.z = aw0*hr[0][6] + aw1*hr[1][6] + aw2*hr[2][6];
        ob.w = aw0*hr[0][7] + aw1*hr[1][7] + aw2*hr[2][7];
        ((float4*)(out + (size_t)i * DD))[2*l16]     = oa;
        ((float4*)(out + (size_t)i * DD))[2*l16 + 1] = ob;
    }
}

// ---------------------------------------------------------------------------
extern "C" void kernel_launch(void* const* d_in, const int* in_sizes, int n_in,
                              void* d_out, int out_size, void* d_ws, size_t ws_size,
                              hipStream_t stream) {
    float* outp = (float*)d_out;
    int fillgrid = (out_size + 255) / 256;
    if (n_in != 17) {                                  // marker: 1024.0
        k_fill<<<fillgrid, 256, 0, stream>>>(outp, 1024.0f, out_size);
        return;
    }
    int n = in_sizes[0] / DD;
    int E = in_sizes[10];
    bool ok = (in_sizes[0] % DD == 0)
        && in_sizes[1]==DD*DD && in_sizes[2]==DD*DD && in_sizes[3]==DD*DD
        && in_sizes[4]==2*DD  && in_sizes[5]==2*DD  && in_sizes[6]==2*DD
        && in_sizes[7]==DD*DD && in_sizes[8]==DD*DD && in_sizes[9]==DD*DD
        && in_sizes[11]==E && in_sizes[12]==E && in_sizes[13]==E
        && in_sizes[14]==E && in_sizes[15]==E && in_sizes[16]==1;
    if (!ok) {                                         // marker: 512.0
        k_fill<<<fillgrid, 256, 0, stream>>>(outp, 512.0f, out_size);
        return;
    }
    int SEG = 3*n;
    int NB1 = (SEG + 255) / 256;
    int tot = 3*E;

    // ws (floats): sl[3n] sr[3n] uv[768] Mf[16384] off[3n] bsum[NB1]
    //              rank[3E] | edat[3E]x2 (8B) | Nbf[n*64] (16B)
    size_t o_edat = (size_t)2*SEG + 768 + DD*DD + SEG + NB1 + (size_t)tot;
    o_edat = (o_edat + 1) & ~(size_t)1;
    size_t o_nbf = o_edat + (size_t)2*tot;
    o_nbf = (o_nbf + 3) & ~(size_t)3;
    size_t need_f = o_nbf + (size_t)n*64;
    if (ws_size < need_f * sizeof(float)) {            // marker: 256.0
        k_fill<<<fillgrid, 256, 0, stream>>>(outp, 256.0f, out_size);
        return;
    }

    const float* N   = (const float*)d_in[0];
    const float* W10 = (const float*)d_in[1];
    const float* W11 = (const float*)d_in[2];
    const float* W12 = (const float*)d_in[3];
    const float* w20 = (const float*)d_in[4];
    const float* w21 = (const float*)d_in[5];
    const float* w22 = (const float*)d_in[6];
    const float* Wq  = (const float*)d_in[7];
    const float* Wk  = (const float*)d_in[8];
    // d_in[9] = Wv — unused in the reference output
    const int* s0 = (const int*)d_in[10];
    const int* d0 = (const int*)d_in[11];
    const int* s1 = (const int*)d_in[12];
    const int* d1 = (const int*)d_in[13];
    const int* s2 = (const int*)d_in[14];
    const int* d2 = (const int*)d_in[15];
    const int* tgt = (const int*)d_in[16];

    float* ws = (float*)d_ws;
    float* sl = ws;
    float* sr = sl + SEG;
    float* uv = sr + SEG;
    float* Mf = uv + 768;
    unsigned* off  = (unsigned*)(Mf + DD*DD);
    unsigned* bsum = off + SEG;
    unsigned* rank = bsum + NB1;
    uint2*    edat = (uint2*)(ws + o_edat);
    unsigned* Nbf  = (unsigned*)(ws + o_nbf);

    k_prep<<<DD + 3, DD, 0, stream>>>(Wq, Wk, W10, W11, W12, w20, w21, w22, Mf, uv);
    k_scores<<<(n + 7)/8, 256, 0, stream>>>(N, uv, sl, sr, (uint2*)Nbf, off, n, SEG);
    k_count<<<(tot + 255)/256, 256, 0, stream>>>(d0, d1, d2, off, rank, n, E);
    k_scan1<<<NB1, 256, 0, stream>>>(off, bsum, SEG);
    k_scan2<<<1, 256, 0, stream>>>(bsum, NB1);
    k_scatter<<<(tot + 255)/256, 256, 0, stream>>>(s0,d0,s1,d1,s2,d2, sl,sr,
                                                   off, bsum, rank, edat, n, E);
    k_node<<<(n + 15)/16, 1024, 0, stream>>>((const uint4*)Nbf, Mf, off, bsum,
                                             edat, tgt, outp, n, tot);
}